// Round 3
// baseline (229.356 us; speedup 1.0000x reference)
//
#include <hip/hip_runtime.h>
#include <hip/hip_fp16.h>

typedef _Float16 half2_t __attribute__((ext_vector_type(2)));
typedef _Float16 half4_t __attribute__((ext_vector_type(4)));
typedef _Float16 half8_t __attribute__((ext_vector_type(8)));
typedef float   float4_t __attribute__((ext_vector_type(4)));

static __device__ __forceinline__ half2_t cvt_pk(float a, float b) {
    return __builtin_bit_cast(half2_t, __builtin_amdgcn_cvt_pkrtz(a, b));
}
static __device__ __forceinline__ half4_t cvt_pk4(float a, float b, float c, float d) {
    half2_t lo = cvt_pk(a, b), hi = cvt_pk(c, d);
    half4_t r;
    r[0] = lo[0]; r[1] = lo[1]; r[2] = hi[0]; r[3] = hi[1];
    return r;
}

namespace {
constexpr int kB      = 16;    // batch
constexpr int kL      = 4096;  // Lq == Lk
constexpr int kD      = 64;    // head dim
constexpr int kQTile  = 128;   // q rows per block (8 waves x 16 rows)
constexpr int kBK     = 64;    // keys per iteration
constexpr int kStride = 72;    // padded LDS row stride (halves)
}

// Flash attention forward, v2: 512-thread blocks (8 waves x 16 q-rows) to lift
// occupancy 8 -> 16 waves/CU (grid is fixed at 512 blocks = 2 blocks/CU).
// S^T = K*Q^T via mfma_f32_16x16x32_f16; its C layout (col=lane&15=q,
// row=4*quad+reg=key) IS the A layout of mfma_f32_16x16x16f16, so P feeds PV
// in-register. l kept as per-lane partial (no per-iter cross-lane reduce);
// O-rescale skipped via wave-uniform ballot when no row max changed.
__global__ __launch_bounds__(512, 4)
void fa_fwd(const float* __restrict__ Q, const float* __restrict__ K,
            const float* __restrict__ V, const float* __restrict__ scale_ptr,
            float* __restrict__ Out)
{
    __shared__ __align__(16) _Float16 Ksh[kBK * kStride];   // Ksh[key][d]
    __shared__ __align__(16) _Float16 Vsh[kD * kStride];    // Vsh[d][key] (transposed)

    const int tid  = threadIdx.x;
    const int wave = tid >> 6;
    const int lane = tid & 63;
    const int c    = lane & 15;   // intra-16 index (q-col in S^T, d-col in O)
    const int qd   = lane >> 4;   // quad 0..3

    const int b  = blockIdx.y;
    const int q0 = blockIdx.x * kQTile + wave * 16;

    // fold 1/scale and log2(e) into Q so softmax uses raw exp2
    const float qscale = 1.4426950408889634f / scale_ptr[0];

    const float* Qb = Q + (size_t)b * kL * kD;
    const float* Kb = K + (size_t)b * kL * kD;
    const float* Vb = V + (size_t)b * kL * kD;

    // ---- Q fragment (B-operand of 16x16x32: n=lane&15=qrow, k=8*quad+j=d) ----
    half8_t qfrag[2];
    {
        const float* qrow = Qb + (size_t)(q0 + c) * kD;
#pragma unroll
        for (int dk = 0; dk < 2; ++dk) {
            const float* p = qrow + dk * 32 + qd * 8;
            half8_t h;
#pragma unroll
            for (int j = 0; j < 8; ++j) h[j] = (_Float16)(p[j] * qscale);
            qfrag[dk] = h;
        }
    }

    float4_t O[4];
#pragma unroll
    for (int dt = 0; dt < 4; ++dt) O[dt] = (float4_t)0.0f;

    float m_run = -__builtin_inff();  // running max for q-row = c
    float lpart = 0.0f;               // per-lane partial sum (q-row = c)

    for (int kb = 0; kb < kL; kb += kBK) {
        __syncthreads();  // protect LDS from previous iteration's readers

        // ---- stage K tile (row-major fp32->fp16), 2 float4 per thread ----
#pragma unroll
        for (int i = 0; i < 2; ++i) {
            const int task = tid + 512 * i;
            const int c4   = task & 15;
            const int row  = task >> 4;
            const float4 f = *(const float4*)(Kb + (size_t)(kb + row) * kD + c4 * 4);
            *(half4_t*)(&Ksh[row * kStride + c4 * 4]) = cvt_pk4(f.x, f.y, f.z, f.w);
        }
        // ---- stage V tile transposed (Vsh[d][key]) ----
#pragma unroll
        for (int i = 0; i < 2; ++i) {
            const int task = tid + 512 * i;
            const int row  = task & 63;
            const int c4   = task >> 6;
            const float4 f = *(const float4*)(Vb + (size_t)(kb + row) * kD + c4 * 4);
            Vsh[(c4 * 4 + 0) * kStride + row] = (_Float16)f.x;
            Vsh[(c4 * 4 + 1) * kStride + row] = (_Float16)f.y;
            Vsh[(c4 * 4 + 2) * kStride + row] = (_Float16)f.z;
            Vsh[(c4 * 4 + 3) * kStride + row] = (_Float16)f.w;
        }
        __syncthreads();

        // ---- K fragments (A-operand: m=lane&15=key, k=8*quad+j=d) ----
        half8_t kf[4][2];
#pragma unroll
        for (int kt = 0; kt < 4; ++kt)
#pragma unroll
            for (int dk = 0; dk < 2; ++dk)
                kf[kt][dk] = *(const half8_t*)(&Ksh[(kt * 16 + c) * kStride + dk * 32 + qd * 8]);

        // ---- S^T = K * Q^T  (C-init = -32: free score shift, overflow margin) ----
        float4_t S[4];
#pragma unroll
        for (int kt = 0; kt < 4; ++kt) {
            float4_t acc = {-32.0f, -32.0f, -32.0f, -32.0f};
            acc = __builtin_amdgcn_mfma_f32_16x16x32_f16(kf[kt][0], qfrag[0], acc, 0, 0, 0);
            acc = __builtin_amdgcn_mfma_f32_16x16x32_f16(kf[kt][1], qfrag[1], acc, 0, 0, 0);
            S[kt] = acc;
        }

        // ---- online softmax (S^T layout: lane column = q-row = c) ----
        float tm = S[0][0];
#pragma unroll
        for (int kt = 0; kt < 4; ++kt)
#pragma unroll
            for (int r = 0; r < 4; ++r) tm = fmaxf(tm, S[kt][r]);
        tm = fmaxf(tm, __shfl_xor(tm, 16));
        tm = fmaxf(tm, __shfl_xor(tm, 32));

        const bool newmax = tm > m_run;
        const unsigned long long upd = __ballot(newmax);
        const float mn = newmax ? tm : m_run;
        if (upd) {  // wave-uniform: skip rescale when no row's max changed
            const float alpha = __builtin_amdgcn_exp2f(m_run - mn);  // 1st iter: 0
            m_run = mn;
            lpart *= alpha;
#pragma unroll
            for (int r = 0; r < 4; ++r) {
                const float a = __shfl(alpha, qd * 4 + r);
#pragma unroll
                for (int dt = 0; dt < 4; ++dt) O[dt][r] *= a;
            }
        }

        // ---- P = exp2(S - m), per-lane l accumulation, pack to fp16 ----
        half4_t pf[4];
#pragma unroll
        for (int kt = 0; kt < 4; ++kt) {
            float p0 = __builtin_amdgcn_exp2f(S[kt][0] - mn);
            float p1 = __builtin_amdgcn_exp2f(S[kt][1] - mn);
            float p2 = __builtin_amdgcn_exp2f(S[kt][2] - mn);
            float p3 = __builtin_amdgcn_exp2f(S[kt][3] - mn);
            lpart += (p0 + p1) + (p2 + p3);
            pf[kt] = cvt_pk4(p0, p1, p2, p3);
        }

        // ---- O += P * V  (B-operand: n=lane&15=d, k=4*quad+i=key) ----
#pragma unroll
        for (int kt = 0; kt < 4; ++kt)
#pragma unroll
            for (int dt = 0; dt < 4; ++dt) {
                const half4_t vf = *(const half4_t*)(&Vsh[(dt * 16 + c) * kStride + kt * 16 + qd * 4]);
                O[dt] = __builtin_amdgcn_mfma_f32_16x16x16f16(pf[kt], vf, O[dt], 0, 0, 0);
            }
    }

    // ---- final l reduction (deferred from the loop) ----
    lpart += __shfl_xor(lpart, 16);
    lpart += __shfl_xor(lpart, 32);

    // ---- epilogue: normalize and store (O row = 4*qd+r, col = dt*16+c) ----
#pragma unroll
    for (int r = 0; r < 4; ++r) {
        const float lr  = __shfl(lpart, qd * 4 + r);
        const float inv = 1.0f / lr;
        const int qrow  = q0 + qd * 4 + r;
        float* op = Out + ((size_t)b * kL + qrow) * kD;
#pragma unroll
        for (int dt = 0; dt < 4; ++dt)
            op[dt * 16 + c] = O[dt][r] * inv;
    }
}

extern "C" void kernel_launch(void* const* d_in, const int* in_sizes, int n_in,
                              void* d_out, int out_size, void* d_ws, size_t ws_size,
                              hipStream_t stream) {
    const float* Q = (const float*)d_in[0];
    const float* K = (const float*)d_in[1];
    const float* V = (const float*)d_in[2];
    const float* s = (const float*)d_in[3];
    float* out = (float*)d_out;
    dim3 grid(kL / kQTile, kB, 1);
    dim3 block(512, 1, 1);
    fa_fwd<<<grid, block, 0, stream>>>(Q, K, V, s, out);
}

// Round 4
// 214.269 us; speedup vs baseline: 1.0704x; 1.0704x over previous
//
#include <hip/hip_runtime.h>
#include <hip/hip_fp16.h>

typedef _Float16 half2_t __attribute__((ext_vector_type(2)));
typedef _Float16 half4_t __attribute__((ext_vector_type(4)));
typedef _Float16 half8_t __attribute__((ext_vector_type(8)));
typedef float   float4_t __attribute__((ext_vector_type(4)));

static __device__ __forceinline__ half2_t cvt_pk(float a, float b) {
    return __builtin_bit_cast(half2_t, __builtin_amdgcn_cvt_pkrtz(a, b));
}
static __device__ __forceinline__ half4_t cvt_pk4(float a, float b, float c, float d) {
    half2_t lo = cvt_pk(a, b), hi = cvt_pk(c, d);
    half4_t r;
    r[0] = lo[0]; r[1] = lo[1]; r[2] = hi[0]; r[3] = hi[1];
    return r;
}

namespace {
constexpr int kB      = 16;    // batch
constexpr int kL      = 4096;  // Lq == Lk
constexpr int kD      = 64;    // head dim
constexpr int kQTile  = 128;   // 4 waves x 32 q-rows (qt=2 amortizes kf/vf LDS reads)
constexpr int kBK     = 64;    // keys per iteration
constexpr int kStride = 72;    // padded LDS row stride (halves)
}

// Flash attention forward, v4 = R1 shape (4 waves x 32 q-rows: kf/vf fragment
// reads amortized over 2 q-tiles — R3 showed un-amortizing them doubles LDS
// conflict cycles for zero gain) + REGISTER PREFETCH: tile i+1's global loads
// are issued right after the compute-opening barrier and consumed at the next
// write phase, so L2/HBM latency overlaps the ~800-cycle compute phase instead
// of serializing inside the barrier pair every iteration.
__global__ __launch_bounds__(256, 2)
void fa_fwd(const float* __restrict__ Q, const float* __restrict__ K,
            const float* __restrict__ V, const float* __restrict__ scale_ptr,
            float* __restrict__ Out)
{
    __shared__ __align__(16) _Float16 Ksh[kBK * kStride];   // Ksh[key][d]
    __shared__ __align__(16) _Float16 Vsh[kD * kStride];    // Vsh[d][key] (transposed)

    const int tid  = threadIdx.x;
    const int wave = tid >> 6;
    const int lane = tid & 63;
    const int c    = lane & 15;   // intra-16 index (q-col in S^T, d-col in O)
    const int qd   = lane >> 4;   // quad 0..3

    const int b  = blockIdx.y;
    const int q0 = blockIdx.x * kQTile + wave * 32;

    // fold 1/scale and log2(e) into Q so softmax uses raw exp2
    const float qscale = 1.4426950408889634f / scale_ptr[0];

    const float* Qb = Q + (size_t)b * kL * kD;
    const float* Kb = K + (size_t)b * kL * kD;
    const float* Vb = V + (size_t)b * kL * kD;

    // ---- Q fragments (B-operand of 16x16x32: n=lane&15=qrow, k=8*quad+j=d) ----
    half8_t qfrag[2][2];
#pragma unroll
    for (int qt = 0; qt < 2; ++qt) {
        const float* qrow = Qb + (size_t)(q0 + qt * 16 + c) * kD;
#pragma unroll
        for (int dk = 0; dk < 2; ++dk) {
            const float* p = qrow + dk * 32 + qd * 8;
            half8_t h;
#pragma unroll
            for (int j = 0; j < 8; ++j) h[j] = (_Float16)(p[j] * qscale);
            qfrag[qt][dk] = h;
        }
    }

    float4_t O[2][4];
#pragma unroll
    for (int qt = 0; qt < 2; ++qt)
#pragma unroll
        for (int dt = 0; dt < 4; ++dt) O[qt][dt] = (float4_t)0.0f;

    float m_run[2] = {-__builtin_inff(), -__builtin_inff()};
    float lpart[2] = {0.0f, 0.0f};

    // ---- prefetch tile 0 into registers ----
    float4 pk[4], pv[4];
#pragma unroll
    for (int i = 0; i < 4; ++i) {
        const int tk = tid + 256 * i;
        pk[i] = *(const float4*)(Kb + (size_t)(tk >> 4) * kD + (tk & 15) * 4);
        pv[i] = *(const float4*)(Vb + (size_t)(tk & 63) * kD + (tk >> 6) * 4);
    }

    for (int kb = 0; kb < kL; kb += kBK) {
        __syncthreads();  // previous tile's readers done; also drains prefetch vmcnt

        // ---- commit prefetched tile to LDS (fp32 -> fp16) ----
#pragma unroll
        for (int i = 0; i < 4; ++i) {
            const int tk = tid + 256 * i;
            *(half4_t*)(&Ksh[(tk >> 4) * kStride + (tk & 15) * 4]) =
                cvt_pk4(pk[i].x, pk[i].y, pk[i].z, pk[i].w);
        }
#pragma unroll
        for (int i = 0; i < 4; ++i) {
            const int tk  = tid + 256 * i;
            const int row = tk & 63;
            const int c4  = tk >> 6;
            Vsh[(c4 * 4 + 0) * kStride + row] = (_Float16)pv[i].x;
            Vsh[(c4 * 4 + 1) * kStride + row] = (_Float16)pv[i].y;
            Vsh[(c4 * 4 + 2) * kStride + row] = (_Float16)pv[i].z;
            Vsh[(c4 * 4 + 3) * kStride + row] = (_Float16)pv[i].w;
        }
        __syncthreads();

        // ---- prefetch NEXT tile (wrap at end -> re-reads tile 0, unused) ----
        {
            const int nb = (kb + kBK) & (kL - 1);
            const float* Kn = Kb + (size_t)nb * kD;
            const float* Vn = Vb + (size_t)nb * kD;
#pragma unroll
            for (int i = 0; i < 4; ++i) {
                const int tk = tid + 256 * i;
                pk[i] = *(const float4*)(Kn + (size_t)(tk >> 4) * kD + (tk & 15) * 4);
                pv[i] = *(const float4*)(Vn + (size_t)(tk & 63) * kD + (tk >> 6) * 4);
            }
        }

        // ---- K fragments (A-operand: m=lane&15=key, k=8*quad+j=d) ----
        half8_t kf[4][2];
#pragma unroll
        for (int kt = 0; kt < 4; ++kt)
#pragma unroll
            for (int dk = 0; dk < 2; ++dk)
                kf[kt][dk] = *(const half8_t*)(&Ksh[(kt * 16 + c) * kStride + dk * 32 + qd * 8]);

        // ---- S^T = K * Q^T  (C-init = -32: free shift, fp16 overflow margin) ----
        float4_t S[4][2];
#pragma unroll
        for (int kt = 0; kt < 4; ++kt)
#pragma unroll
            for (int qt = 0; qt < 2; ++qt) {
                float4_t acc = {-32.0f, -32.0f, -32.0f, -32.0f};
                acc = __builtin_amdgcn_mfma_f32_16x16x32_f16(kf[kt][0], qfrag[qt][0], acc, 0, 0, 0);
                acc = __builtin_amdgcn_mfma_f32_16x16x32_f16(kf[kt][1], qfrag[qt][1], acc, 0, 0, 0);
                S[kt][qt] = acc;
            }

        // ---- online softmax per q-tile (S^T layout: lane column = q-row = c) ----
        half4_t pf[4][2];
#pragma unroll
        for (int qt = 0; qt < 2; ++qt) {
            float tm = S[0][qt][0];
#pragma unroll
            for (int kt = 0; kt < 4; ++kt)
#pragma unroll
                for (int r = 0; r < 4; ++r) tm = fmaxf(tm, S[kt][qt][r]);
            tm = fmaxf(tm, __shfl_xor(tm, 16));
            tm = fmaxf(tm, __shfl_xor(tm, 32));

            const bool newmax = tm > m_run[qt];
            const float mn = newmax ? tm : m_run[qt];
            if (__ballot(newmax)) {  // wave-uniform: skip rescale when no row max moved
                const float alpha = __builtin_amdgcn_exp2f(m_run[qt] - mn);  // 1st iter: 0
                m_run[qt] = mn;
                lpart[qt] *= alpha;
#pragma unroll
                for (int r = 0; r < 4; ++r) {
                    const float a = __shfl(alpha, qd * 4 + r);
#pragma unroll
                    for (int dt = 0; dt < 4; ++dt) O[qt][dt][r] *= a;
                }
            }

            // P = exp2(S - m), per-lane partial l, pack to fp16 A-fragments
#pragma unroll
            for (int kt = 0; kt < 4; ++kt) {
                const float p0 = __builtin_amdgcn_exp2f(S[kt][qt][0] - mn);
                const float p1 = __builtin_amdgcn_exp2f(S[kt][qt][1] - mn);
                const float p2 = __builtin_amdgcn_exp2f(S[kt][qt][2] - mn);
                const float p3 = __builtin_amdgcn_exp2f(S[kt][qt][3] - mn);
                lpart[qt] += (p0 + p1) + (p2 + p3);
                pf[kt][qt] = cvt_pk4(p0, p1, p2, p3);
            }
        }

        // ---- O += P * V  (vf shared across both q-tiles) ----
#pragma unroll
        for (int kt = 0; kt < 4; ++kt)
#pragma unroll
            for (int dt = 0; dt < 4; ++dt) {
                const half4_t vf = *(const half4_t*)(&Vsh[(dt * 16 + c) * kStride + kt * 16 + qd * 4]);
#pragma unroll
                for (int qt = 0; qt < 2; ++qt)
                    O[qt][dt] = __builtin_amdgcn_mfma_f32_16x16x16f16(pf[kt][qt], vf, O[qt][dt], 0, 0, 0);
            }
    }

    // ---- final l reduction (deferred from the loop) ----
#pragma unroll
    for (int qt = 0; qt < 2; ++qt) {
        lpart[qt] += __shfl_xor(lpart[qt], 16);
        lpart[qt] += __shfl_xor(lpart[qt], 32);
    }

    // ---- epilogue: normalize and store (O row = 4*qd+r, col = dt*16+c) ----
#pragma unroll
    for (int qt = 0; qt < 2; ++qt)
#pragma unroll
        for (int r = 0; r < 4; ++r) {
            const float lr  = __shfl(lpart[qt], qd * 4 + r);
            const float inv = 1.0f / lr;
            const int qrow  = q0 + qt * 16 + qd * 4 + r;
            float* op = Out + ((size_t)b * kL + qrow) * kD;
#pragma unroll
            for (int dt = 0; dt < 4; ++dt)
                op[dt * 16 + c] = O[qt][dt][r] * inv;
        }
}

extern "C" void kernel_launch(void* const* d_in, const int* in_sizes, int n_in,
                              void* d_out, int out_size, void* d_ws, size_t ws_size,
                              hipStream_t stream) {
    const float* Q = (const float*)d_in[0];
    const float* K = (const float*)d_in[1];
    const float* V = (const float*)d_in[2];
    const float* s = (const float*)d_in[3];
    float* out = (float*)d_out;
    dim3 grid(kL / kQTile, kB, 1);
    dim3 block(256, 1, 1);
    fa_fwd<<<grid, block, 0, stream>>>(Q, K, V, s, out);
}